// Round 3
// baseline (1130.129 us; speedup 1.0000x reference)
//
#include <hip/hip_runtime.h>
#include <hip/hip_bf16.h>

#define NN 6000
#define NPAD 6016      // 94*64
#define DF 512
#define HID 256
#define NH 8
#define NC 32
#define FTOT 2048
#define MSTR 96        // u64 words per mask row

using short8 = __attribute__((ext_vector_type(8))) short;
using f32x16 = __attribute__((ext_vector_type(16))) float;
using f32x4  = __attribute__((ext_vector_type(4))) float;

__device__ __forceinline__ unsigned short f2bf(float f) {
    unsigned int u = __float_as_uint(f);
    return (unsigned short)((u + 0x7fffu + ((u >> 16) & 1u)) >> 16);
}
__device__ __forceinline__ float bf2f(unsigned short s) {
    return __uint_as_float(((unsigned int)s) << 16);
}
// async global->LDS, 16B per lane; LDS dest = wave-uniform base + lane*16
__device__ __forceinline__ void gl16(const void* g, void* l) {
    __builtin_amdgcn_global_load_lds(
        (const __attribute__((address_space(1))) unsigned int*)g,
        (__attribute__((address_space(3))) unsigned int*)l, 16, 0, 0);
}

// ---------------- prep kernels (NEW set under test) ----------------

// adj [6000][6000] i32 -> bitmask bytes [6000][768] (bit j of row; pad zero)
__global__ void pack_bits(const int* __restrict__ adj, unsigned char* __restrict__ maskb) {
    int row = blockIdx.y;
    int b = blockIdx.x * 256 + threadIdx.x;     // byte index 0..767
    if (b >= 768) return;
    int j0 = b * 8;
    unsigned int v = 0;
    if (j0 + 7 < NN) {
        const int4* p = (const int4*)(adj + (size_t)row * NN + j0);
        int4 a = p[0], c = p[1];
        v = (unsigned)((a.x>0) | ((a.y>0)<<1) | ((a.z>0)<<2) | ((a.w>0)<<3)
          | ((c.x>0)<<4) | ((c.y>0)<<5) | ((c.z>0)<<6) | ((c.w>0)<<7));
    }
    maskb[(size_t)row * 768 + b] = (unsigned char)v;
}

__global__ void cast_x4(const float* __restrict__ x, unsigned short* __restrict__ xb, int n4) {
    int i = blockIdx.x * 256 + threadIdx.x;
    if (i >= n4) return;
    float4 v = ((const float4*)x)[i];
    unsigned long long pk = (unsigned long long)f2bf(v.x)
        | ((unsigned long long)f2bf(v.y) << 16)
        | ((unsigned long long)f2bf(v.z) << 32)
        | ((unsigned long long)f2bf(v.w) << 48);
    ((unsigned long long*)xb)[i] = pk;
}

// W0 [8][512][256] -> Wt [2048][512]
__global__ void wt_pack(const float* __restrict__ W0, unsigned short* __restrict__ Wt) {
    int fp = blockIdx.x;                 // h*256+f
    int h = fp >> 8, f = fp & 255;
    for (int k = threadIdx.x; k < DF; k += 256)
        Wt[(size_t)fp * DF + k] = f2bf(W0[(((size_t)h * DF + k) << 8) | f]);
}

// Wc [2048][32] -> Wct [32][2048]
__global__ void wct_pack(const float* __restrict__ Wc, unsigned short* __restrict__ Wct) {
    int c = blockIdx.x;
    for (int k = threadIdx.x; k < FTOT; k += 256)
        Wct[(size_t)c * FTOT + k] = f2bf(Wc[(size_t)k * NC + c]);
}

// ---------------- GEMM1 (NEW): Ht[f][i] = sum_k X[i][k] W[k][f] ----------------
__global__ __launch_bounds__(256, 2) void gemm_h(const unsigned short* __restrict__ A,   // Xbf [6000][512]
                                                 const unsigned short* __restrict__ B,   // Wt  [2048][512]
                                                 unsigned short* __restrict__ Ht) {      // [2048][NPAD]
    __shared__ __align__(16) unsigned short As[128 * 64];   // swizzled, 16KB
    __shared__ __align__(16) unsigned short Bs[128 * 64];
    const int w = threadIdx.x >> 6, l = threadIdx.x & 63;
    const int lrow = l & 31, kh = l >> 5;
    const int wm = w >> 1, wn = w & 1;
    const int mbase = blockIdx.x * 128, nbase = blockIdx.y * 128;
    const int srcc = (l & 7) ^ (l >> 3);
    f32x16 acc[2][2];
#pragma unroll
    for (int i = 0; i < 2; ++i)
#pragma unroll
        for (int j = 0; j < 2; ++j) acc[i][j] = (f32x16)0.0f;

#pragma unroll 1
    for (int kb = 0; kb < DF / 64; ++kb) {
        __syncthreads();
#pragma unroll
        for (int q = 0; q < 4; ++q) {
            int c = q * 4 + w;                       // 16B-chunk call 0..15
            int r = c * 8 + (l >> 3);                // tile row 0..127
            int arow = mbase + r; if (arow > NN - 1) arow = NN - 1;   // clamp keeps pad finite
            gl16(A + (size_t)arow * DF + kb * 64 + srcc * 8, (char*)As + c * 1024);
            gl16(B + (size_t)(nbase + r) * DF + kb * 64 + srcc * 8, (char*)Bs + c * 1024);
        }
        __syncthreads();
#pragma unroll
        for (int kk = 0; kk < 4; ++kk) {
            short8 av[2], bv[2];
#pragma unroll
            for (int mt = 0; mt < 2; ++mt) {
                int r = wm * 64 + mt * 32 + lrow;
                av[mt] = *(const short8*)((const char*)As + r * 128 + ((((kk << 1) | kh) ^ (r & 7)) << 4));
            }
#pragma unroll
            for (int ft = 0; ft < 2; ++ft) {
                int r = wn * 64 + ft * 32 + lrow;
                bv[ft] = *(const short8*)((const char*)Bs + r * 128 + ((((kk << 1) | kh) ^ (r & 7)) << 4));
            }
#pragma unroll
            for (int mt = 0; mt < 2; ++mt)
#pragma unroll
                for (int ft = 0; ft < 2; ++ft)
                    acc[mt][ft] = __builtin_amdgcn_mfma_f32_32x32x16_bf16(av[mt], bv[ft], acc[mt][ft], 0, 0, 0);
        }
    }
    // D: col(lane&31) = B-row n, row(reg-mapped) = A-row m  (round-1-verified mapping)
#pragma unroll
    for (int mt = 0; mt < 2; ++mt)
#pragma unroll
        for (int ft = 0; ft < 2; ++ft) {
            size_t n = nbase + wn * 64 + ft * 32 + lrow;
#pragma unroll
            for (int g = 0; g < 4; ++g) {
                int m0 = mbase + wm * 64 + mt * 32 + (g << 3) + (kh << 2);
                unsigned long long pk =
                    (unsigned long long)f2bf(acc[mt][ft][g * 4 + 0]) |
                    ((unsigned long long)f2bf(acc[mt][ft][g * 4 + 1]) << 16) |
                    ((unsigned long long)f2bf(acc[mt][ft][g * 4 + 2]) << 32) |
                    ((unsigned long long)f2bf(acc[mt][ft][g * 4 + 3]) << 48);
                *(unsigned long long*)(Ht + n * NPAD + m0) = pk;
            }
        }
}

// ---------------- round-1-verified kernels below (byte-for-byte) ----------------

// f1[h][i] = sum_f Ht[h*fdim+f][i]*a1[h*fdim+f]; f2 likewise
__global__ void f12_kern(const unsigned short* __restrict__ Ht, const float* __restrict__ a1,
                         const float* __restrict__ a2, float* __restrict__ f1, float* __restrict__ f2,
                         int fdim) {
    int h = blockIdx.y;
    int i = blockIdx.x * 256 + threadIdx.x;
    if (i >= NPAD) return;
    float s1 = 0.f, s2 = 0.f;
    const unsigned short* base = Ht + (size_t)h * fdim * NPAD + i;
    for (int f = 0; f < fdim; ++f) {
        float v = bf2f(base[(size_t)f * NPAD]);
        s1 = fmaf(v, a1[h * fdim + f], s1);
        s2 = fmaf(v, a2[h * fdim + f], s2);
    }
    f1[h * NPAD + i] = s1;
    f2[h * NPAD + i] = s2;
}

// per (h,i): m = max_{j in N(i)} f2[j]; M = lrelu(f1+m); RA = f1-M; RB = 0.2*f1-M
// NEW: f2 row staged in LDS once per block (was a per-row L2 gather)
__global__ __launch_bounds__(256, 4) void prep_rows(const unsigned long long* __restrict__ mask,
                          const float* __restrict__ f1all, const float* __restrict__ f2all,
                          float* __restrict__ RA, float* __restrict__ RB) {
    __shared__ float lf2[NPAD];
    int h = blockIdx.y;
    const float* f2h = f2all + (size_t)h * NPAD;
    for (int q = threadIdx.x; q < NPAD / 4; q += 256)
        ((float4*)lf2)[q] = ((const float4*)f2h)[q];
    __syncthreads();
    int w = threadIdx.x >> 6, lane = threadIdx.x & 63;
    int i0 = blockIdx.x * 64 + w * 16;
    for (int rr = 0; rr < 16; ++rr) {
        int i = i0 + rr;
        float m = -3.0e38f;
        if (i < NN) {
            const unsigned long long* mrow = mask + (size_t)i * MSTR;
            for (int t = 0; t < 94; ++t) {
                unsigned long long wb = mrow[t];
                if ((wb >> lane) & 1ull) m = fmaxf(m, lf2[t * 64 + lane]);
            }
        }
        for (int off = 32; off; off >>= 1) m = fmaxf(m, __shfl_xor(m, off));
        if (lane == 0) {
            float F1 = 0.f, M = 0.f;
            if (i < NN) {
                F1 = f1all[(size_t)h * NPAD + i];
                float t2 = F1 + m;
                M = fmaxf(t2, 0.2f * t2);
            }
            RA[(size_t)h * NPAD + i] = F1 - M;
            RB[(size_t)h * NPAD + i] = 0.2f * F1 - M;
        }
    }
}

__global__ void prep_f2s(const float* __restrict__ f2, float* __restrict__ F2,
                         float* __restrict__ F2b, int n) {
    int i = blockIdx.x * blockDim.x + threadIdx.x;
    if (i < n) { float v = f2[i]; F2[i] = v; F2b[i] = 0.2f * v; }
}

// ---------------- flash-style masked softmax-aggregation (round-1 verbatim) ----------------
template<int F, bool STORE_X2>
__global__ __launch_bounds__(256, 2) void attn_kern(
    const unsigned short* __restrict__ Hall,          // [nh*F][NPAD] (transposed h)
    const unsigned long long* __restrict__ mask,
    const float* __restrict__ RA, const float* __restrict__ RB,
    const float* __restrict__ F2, const float* __restrict__ F2b,
    unsigned short* __restrict__ x2, float* __restrict__ outp)
{
    constexpr int NT = F / 32;
    __shared__ __align__(16) unsigned short htile[F * 64];   // [F][64] swizzled
    __shared__ unsigned int mtile[128 * 2];

    const int w = threadIdx.x >> 6, l = threadIdx.x & 63;
    const int lrow = l & 31, kh = l >> 5;
    const int h = blockIdx.y;
    const int rowbase = blockIdx.x * 128;
    const int myrow = rowbase + w * 32 + lrow;

    const unsigned short* Hh = Hall + (size_t)h * F * NPAD;
    const float* RAh = RA + h * NPAD;
    const float* RBh = RB + h * NPAD;
    const float* F2h = F2 + h * NPAD;
    const float* F2bh = F2b + h * NPAD;

    const float ra = RAh[myrow], rb = RBh[myrow];
    float dsum = 0.f;
    f32x16 acc[NT];
#pragma unroll
    for (int i = 0; i < NT; ++i) acc[i] = (f32x16)0.0f;

    for (int jb = 0; jb < NPAD / 64; ++jb) {
        __syncthreads();
        constexpr int CPT = (F * 8) / 256;
#pragma unroll
        for (int cc = 0; cc < CPT; ++cc) {
            int idx = threadIdx.x + cc * 256;
            int f = idx >> 3, c = idx & 7;
            uint4 g = *(const uint4*)(Hh + (size_t)f * NPAD + jb * 64 + c * 8);
            int byt = f * 128 + ((c * 16) ^ ((f & 7) << 4));
            *(uint4*)((char*)htile + byt) = g;
        }
        {
            int r = threadIdx.x >> 1, half = threadIdx.x & 1;
            int grow = rowbase + r;
            unsigned int mv = 0;
            if (grow < NN) mv = ((const unsigned int*)(mask + (size_t)grow * MSTR))[jb * 2 + half];
            mtile[r * 2 + half] = mv;
        }
        __syncthreads();
#pragma unroll
        for (int kk = 0; kk < 4; ++kk) {
            unsigned int mword = mtile[(w * 32 + lrow) * 2 + (kk >> 1)];
            unsigned int mbyte = (mword >> (((kk & 1) * 2 + kh) * 8)) & 0xffu;
            int j0 = jb * 64 + kk * 16 + kh * 8;
            f32x4 fa0 = *(const f32x4*)(F2h + j0);
            f32x4 fa1 = *(const f32x4*)(F2h + j0 + 4);
            f32x4 fb0 = *(const f32x4*)(F2bh + j0);
            f32x4 fb1 = *(const f32x4*)(F2bh + j0 + 4);
            short8 afrag;
#pragma unroll
            for (int e = 0; e < 8; ++e) {
                float fe = (e < 4) ? fa0[e & 3] : fa1[e & 3];
                float fb = (e < 4) ? fb0[e & 3] : fb1[e & 3];
                float p = __expf(fmaxf(ra + fe, rb + fb));
                p = ((mbyte >> e) & 1u) ? p : 0.f;
                dsum += p;
                afrag[e] = (short)f2bf(p);
            }
#pragma unroll
            for (int ft = 0; ft < NT; ++ft) {
                int fr = ft * 32 + lrow;
                int byt = fr * 128 + (((kk * 2 + kh) * 16) ^ ((fr & 7) << 4));
                short8 bfrag = *(const short8*)((char*)htile + byt);
                acc[ft] = __builtin_amdgcn_mfma_f32_32x32x16_bf16(afrag, bfrag, acc[ft], 0, 0, 0);
            }
        }
    }
    dsum += __shfl_xor(dsum, 32);
    float dinv = (dsum > 0.f) ? (1.0f / dsum) : 0.f;
    float rcp16[16];
#pragma unroll
    for (int g = 0; g < 4; ++g)
#pragma unroll
        for (int r = 0; r < 4; ++r)
            rcp16[g * 4 + r] = __shfl(dinv, (g << 3) + (kh << 2) + r);

    if constexpr (!STORE_X2) {
        // classifier: write fp32 out[i][c], c = lrow
#pragma unroll
        for (int g = 0; g < 4; ++g)
#pragma unroll
            for (int r = 0; r < 4; ++r) {
                int grow = rowbase + w * 32 + (g << 3) + (kh << 2) + r;
                if (grow < NN) outp[(size_t)grow * NC + lrow] = acc[0][g * 4 + r] * rcp16[g * 4 + r];
            }
    } else {
        // ELU + bf16 store of x2[i][h*256+f] via LDS transpose (2 waves per phase)
        unsigned short* tb = htile;
        for (int ph = 0; ph < 2; ++ph) {
            __syncthreads();
            if ((w >> 1) == ph) {
                unsigned short* wb = tb + (w & 1) * (32 * 256);
#pragma unroll
                for (int ft = 0; ft < NT; ++ft)
#pragma unroll
                    for (int g = 0; g < 4; ++g)
#pragma unroll
                        for (int r = 0; r < 4; ++r) {
                            int lr2 = (g << 3) + (kh << 2) + r;
                            float v = acc[ft][g * 4 + r] * rcp16[g * 4 + r];
                            v = (v > 0.f) ? v : (__expf(v) - 1.f);
                            wb[lr2 * 256 + ft * 32 + lrow] = f2bf(v);
                        }
            }
            __syncthreads();
            if ((w >> 1) == ph) {
                unsigned short* wb = tb + (w & 1) * (32 * 256);
                int r = l >> 1;
                int grow = rowbase + w * 32 + r;
                if (grow < NN) {
#pragma unroll
                    for (int it = 0; it < 16; ++it) {
                        int c = (l & 1) * 16 + it;
                        uint4 v = *(const uint4*)(wb + r * 256 + c * 8);
                        *(uint4*)(x2 + (size_t)grow * FTOT + h * HID + c * 8) = v;
                    }
                }
            }
        }
    }
}

// ---------------- GEMM2 (round-1 verbatim): hct[c][i] = sum_k Wc[k][c] x2[i][k] ----------------
__global__ __launch_bounds__(256, 2) void gemm_hc(const unsigned short* __restrict__ A,  // Wct [32][2048]
                                                  const unsigned short* __restrict__ B,  // x2 [6000][2048]
                                                  unsigned short* __restrict__ hct) {    // [32][NPAD]
    int w = threadIdx.x >> 6, l = threadIdx.x & 63;
    int lrow = l & 31, kh = l >> 5;
    int nbase = blockIdx.x * 128 + w * 32;
    int brow = nbase + lrow; if (brow > NN - 1) brow = NN - 1;
    f32x16 acc = (f32x16)0.0f;
    const short8* ap = (const short8*)(A + (size_t)lrow * FTOT + kh * 8);
    const short8* bp = (const short8*)(B + (size_t)brow * FTOT + kh * 8);
    for (int kk = 0; kk < FTOT / 16; ++kk) {
        short8 af = ap[kk * 2];
        short8 bf = bp[kk * 2];
        acc = __builtin_amdgcn_mfma_f32_32x32x16_bf16(af, bf, acc, 0, 0, 0);
    }
    int i = nbase + lrow;   // col = i
#pragma unroll
    for (int g = 0; g < 4; ++g) {
        int c0 = (g << 3) + (kh << 2);
#pragma unroll
        for (int r = 0; r < 4; ++r)
            hct[(size_t)(c0 + r) * NPAD + i] = f2bf(acc[g * 4 + r]);
    }
}

// ---------------- launcher ----------------
extern "C" void kernel_launch(void* const* d_in, const int* in_sizes, int n_in,
                              void* d_out, int out_size, void* d_ws, size_t ws_size,
                              hipStream_t stream) {
    const float* features = (const float*)d_in[0];
    const int*   adj      = (const int*)d_in[1];
    const float* W0       = (const float*)d_in[2];
    const float* a10      = (const float*)d_in[3];
    const float* a20      = (const float*)d_in[4];
    const float* Wc       = (const float*)d_in[5];
    const float* a1c      = (const float*)d_in[6];
    const float* a2c      = (const float*)d_in[7];
    float* out = (float*)d_out;

    char* p = (char*)d_ws;
    auto alloc = [&](size_t bytes) { char* r = p; p += (bytes + 255) & ~(size_t)255; return r; };
    unsigned long long* mask = (unsigned long long*)alloc((size_t)NN * MSTR * 8);
    unsigned short* Xbf = (unsigned short*)alloc((size_t)NN * DF * 2);
    unsigned short* Wt  = (unsigned short*)alloc((size_t)FTOT * DF * 2);
    unsigned short* Ht  = (unsigned short*)alloc((size_t)FTOT * NPAD * 2);
    unsigned short* x2  = (unsigned short*)alloc((size_t)NN * FTOT * 2);
    unsigned short* Wct = (unsigned short*)alloc((size_t)NC * FTOT * 2);
    unsigned short* hct = (unsigned short*)alloc((size_t)NC * NPAD * 2);
    float* f1  = (float*)alloc((size_t)NH * NPAD * 4);
    float* f2  = (float*)alloc((size_t)NH * NPAD * 4);
    float* RA  = (float*)alloc((size_t)NH * NPAD * 4);
    float* RB  = (float*)alloc((size_t)NH * NPAD * 4);
    float* F2  = (float*)alloc((size_t)NH * NPAD * 4);
    float* F2b = (float*)alloc((size_t)NH * NPAD * 4);
    float* f1c  = (float*)alloc((size_t)NPAD * 4);
    float* f2c  = (float*)alloc((size_t)NPAD * 4);
    float* RAc  = (float*)alloc((size_t)NPAD * 4);
    float* RBc  = (float*)alloc((size_t)NPAD * 4);
    float* F2c  = (float*)alloc((size_t)NPAD * 4);
    float* F2cb = (float*)alloc((size_t)NPAD * 4);

    pack_bits<<<dim3(3, NN), 256, 0, stream>>>(adj, (unsigned char*)mask);
    cast_x4<<<(NN * DF / 4 + 255) / 256, 256, 0, stream>>>(features, Xbf, NN * DF / 4);
    wt_pack<<<FTOT, 256, 0, stream>>>(W0, Wt);
    wct_pack<<<NC, 256, 0, stream>>>(Wc, Wct);

    gemm_h<<<dim3(NPAD / 128, FTOT / 128), 256, 0, stream>>>(Xbf, Wt, Ht);
    f12_kern<<<dim3((NPAD + 255) / 256, NH), 256, 0, stream>>>(Ht, a10, a20, f1, f2, HID);
    prep_rows<<<dim3(94, NH), 256, 0, stream>>>(mask, f1, f2, RA, RB);
    prep_f2s<<<(NH * NPAD + 255) / 256, 256, 0, stream>>>(f2, F2, F2b, NH * NPAD);

    attn_kern<HID, true><<<dim3(NPAD / 128, NH), 256, 0, stream>>>(Ht, mask, RA, RB, F2, F2b, x2, nullptr);

    gemm_hc<<<NPAD / 128, 256, 0, stream>>>(Wct, x2, hct);
    f12_kern<<<dim3((NPAD + 255) / 256, 1), 256, 0, stream>>>(hct, a1c, a2c, f1c, f2c, NC);
    prep_rows<<<dim3(94, 1), 256, 0, stream>>>(mask, f1c, f2c, RAc, RBc);
    prep_f2s<<<(NPAD + 255) / 256, 256, 0, stream>>>(f2c, F2c, F2cb, NPAD);

    attn_kern<NC, false><<<dim3(NPAD / 128, 1), 256, 0, stream>>>(hct, mask, RAc, RBc, F2c, F2cb, nullptr, out);
}

// Round 4
// 945.410 us; speedup vs baseline: 1.1954x; 1.1954x over previous
//
#include <hip/hip_runtime.h>
#include <hip/hip_bf16.h>

#define NN 6000
#define NPAD 6016      // 94*64
#define DF 512
#define HID 256
#define NH 8
#define NC 32
#define FTOT 2048
#define MSTR 96        // u64 words per mask row

using short8 = __attribute__((ext_vector_type(8))) short;
using f32x16 = __attribute__((ext_vector_type(16))) float;
using f32x4  = __attribute__((ext_vector_type(4))) float;

__device__ __forceinline__ unsigned short f2bf(float f) {
    unsigned int u = __float_as_uint(f);
    return (unsigned short)((u + 0x7fffu + ((u >> 16) & 1u)) >> 16);
}
__device__ __forceinline__ float bf2f(unsigned short s) {
    return __uint_as_float(((unsigned int)s) << 16);
}
// async global->LDS, 16B per lane; LDS dest = wave-uniform base + lane*16
__device__ __forceinline__ void gl16(const void* g, void* l) {
    __builtin_amdgcn_global_load_lds(
        (const __attribute__((address_space(1))) unsigned int*)g,
        (__attribute__((address_space(3))) unsigned int*)l, 16, 0, 0);
}

// ---------------- prep kernels (round-3 verified) ----------------

__global__ void pack_bits(const int* __restrict__ adj, unsigned char* __restrict__ maskb) {
    int row = blockIdx.y;
    int b = blockIdx.x * 256 + threadIdx.x;     // byte index 0..767
    if (b >= 768) return;
    int j0 = b * 8;
    unsigned int v = 0;
    if (j0 + 7 < NN) {
        const int4* p = (const int4*)(adj + (size_t)row * NN + j0);
        int4 a = p[0], c = p[1];
        v = (unsigned)((a.x>0) | ((a.y>0)<<1) | ((a.z>0)<<2) | ((a.w>0)<<3)
          | ((c.x>0)<<4) | ((c.y>0)<<5) | ((c.z>0)<<6) | ((c.w>0)<<7));
    }
    maskb[(size_t)row * 768 + b] = (unsigned char)v;
}

__global__ void cast_x4(const float* __restrict__ x, unsigned short* __restrict__ xb, int n4) {
    int i = blockIdx.x * 256 + threadIdx.x;
    if (i >= n4) return;
    float4 v = ((const float4*)x)[i];
    unsigned long long pk = (unsigned long long)f2bf(v.x)
        | ((unsigned long long)f2bf(v.y) << 16)
        | ((unsigned long long)f2bf(v.z) << 32)
        | ((unsigned long long)f2bf(v.w) << 48);
    ((unsigned long long*)xb)[i] = pk;
}

__global__ void wt_pack(const float* __restrict__ W0, unsigned short* __restrict__ Wt) {
    int fp = blockIdx.x;                 // h*256+f
    int h = fp >> 8, f = fp & 255;
    for (int k = threadIdx.x; k < DF; k += 256)
        Wt[(size_t)fp * DF + k] = f2bf(W0[(((size_t)h * DF + k) << 8) | f]);
}

__global__ void wct_pack(const float* __restrict__ Wc, unsigned short* __restrict__ Wct) {
    int c = blockIdx.x;
    for (int k = threadIdx.x; k < FTOT; k += 256)
        Wct[(size_t)c * FTOT + k] = f2bf(Wc[(size_t)k * NC + c]);
}

// ---------------- GEMM1 (round-3 verified): Ht[f][i] = sum_k X[i][k] W[k][f] ----------------
__global__ __launch_bounds__(256, 2) void gemm_h(const unsigned short* __restrict__ A,
                                                 const unsigned short* __restrict__ B,
                                                 unsigned short* __restrict__ Ht) {
    __shared__ __align__(16) unsigned short As[128 * 64];
    __shared__ __align__(16) unsigned short Bs[128 * 64];
    const int w = threadIdx.x >> 6, l = threadIdx.x & 63;
    const int lrow = l & 31, kh = l >> 5;
    const int wm = w >> 1, wn = w & 1;
    const int mbase = blockIdx.x * 128, nbase = blockIdx.y * 128;
    const int srcc = (l & 7) ^ (l >> 3);
    f32x16 acc[2][2];
#pragma unroll
    for (int i = 0; i < 2; ++i)
#pragma unroll
        for (int j = 0; j < 2; ++j) acc[i][j] = (f32x16)0.0f;

#pragma unroll 1
    for (int kb = 0; kb < DF / 64; ++kb) {
        __syncthreads();
#pragma unroll
        for (int q = 0; q < 4; ++q) {
            int c = q * 4 + w;
            int r = c * 8 + (l >> 3);
            int arow = mbase + r; if (arow > NN - 1) arow = NN - 1;
            gl16(A + (size_t)arow * DF + kb * 64 + srcc * 8, (char*)As + c * 1024);
            gl16(B + (size_t)(nbase + r) * DF + kb * 64 + srcc * 8, (char*)Bs + c * 1024);
        }
        __syncthreads();
#pragma unroll
        for (int kk = 0; kk < 4; ++kk) {
            short8 av[2], bv[2];
#pragma unroll
            for (int mt = 0; mt < 2; ++mt) {
                int r = wm * 64 + mt * 32 + lrow;
                av[mt] = *(const short8*)((const char*)As + r * 128 + ((((kk << 1) | kh) ^ (r & 7)) << 4));
            }
#pragma unroll
            for (int ft = 0; ft < 2; ++ft) {
                int r = wn * 64 + ft * 32 + lrow;
                bv[ft] = *(const short8*)((const char*)Bs + r * 128 + ((((kk << 1) | kh) ^ (r & 7)) << 4));
            }
#pragma unroll
            for (int mt = 0; mt < 2; ++mt)
#pragma unroll
                for (int ft = 0; ft < 2; ++ft)
                    acc[mt][ft] = __builtin_amdgcn_mfma_f32_32x32x16_bf16(av[mt], bv[ft], acc[mt][ft], 0, 0, 0);
        }
    }
#pragma unroll
    for (int mt = 0; mt < 2; ++mt)
#pragma unroll
        for (int ft = 0; ft < 2; ++ft) {
            size_t n = nbase + wn * 64 + ft * 32 + lrow;
#pragma unroll
            for (int g = 0; g < 4; ++g) {
                int m0 = mbase + wm * 64 + mt * 32 + (g << 3) + (kh << 2);
                unsigned long long pk =
                    (unsigned long long)f2bf(acc[mt][ft][g * 4 + 0]) |
                    ((unsigned long long)f2bf(acc[mt][ft][g * 4 + 1]) << 16) |
                    ((unsigned long long)f2bf(acc[mt][ft][g * 4 + 2]) << 32) |
                    ((unsigned long long)f2bf(acc[mt][ft][g * 4 + 3]) << 48);
                *(unsigned long long*)(Ht + n * NPAD + m0) = pk;
            }
        }
}

// ---------------- f1/f2 (round-3 verified) ----------------
__global__ void f12_kern(const unsigned short* __restrict__ Ht, const float* __restrict__ a1,
                         const float* __restrict__ a2, float* __restrict__ f1, float* __restrict__ f2,
                         int fdim) {
    int h = blockIdx.y;
    int i = blockIdx.x * 256 + threadIdx.x;
    if (i >= NPAD) return;
    float s1 = 0.f, s2 = 0.f;
    const unsigned short* base = Ht + (size_t)h * fdim * NPAD + i;
    for (int f = 0; f < fdim; ++f) {
        float v = bf2f(base[(size_t)f * NPAD]);
        s1 = fmaf(v, a1[h * fdim + f], s1);
        s2 = fmaf(v, a2[h * fdim + f], s2);
    }
    f1[h * NPAD + i] = s1;
    f2[h * NPAD + i] = s2;
}

// ---------------- prep_rows (round-3 verified) ----------------
__global__ __launch_bounds__(256, 4) void prep_rows(const unsigned long long* __restrict__ mask,
                          const float* __restrict__ f1all, const float* __restrict__ f2all,
                          float* __restrict__ RA, float* __restrict__ RB) {
    __shared__ float lf2[NPAD];
    int h = blockIdx.y;
    const float* f2h = f2all + (size_t)h * NPAD;
    for (int q = threadIdx.x; q < NPAD / 4; q += 256)
        ((float4*)lf2)[q] = ((const float4*)f2h)[q];
    __syncthreads();
    int w = threadIdx.x >> 6, lane = threadIdx.x & 63;
    int i0 = blockIdx.x * 64 + w * 16;
    for (int rr = 0; rr < 16; ++rr) {
        int i = i0 + rr;
        float m = -3.0e38f;
        if (i < NN) {
            const unsigned long long* mrow = mask + (size_t)i * MSTR;
            for (int t = 0; t < 94; ++t) {
                unsigned long long wb = mrow[t];
                if ((wb >> lane) & 1ull) m = fmaxf(m, lf2[t * 64 + lane]);
            }
        }
        for (int off = 32; off; off >>= 1) m = fmaxf(m, __shfl_xor(m, off));
        if (lane == 0) {
            float F1 = 0.f, M = 0.f;
            if (i < NN) {
                F1 = f1all[(size_t)h * NPAD + i];
                float t2 = F1 + m;
                M = fmaxf(t2, 0.2f * t2);
            }
            RA[(size_t)h * NPAD + i] = F1 - M;
            RB[(size_t)h * NPAD + i] = 0.2f * F1 - M;
        }
    }
}

__global__ void prep_f2s(const float* __restrict__ f2, float* __restrict__ F2,
                         float* __restrict__ F2b, int n) {
    int i = blockIdx.x * blockDim.x + threadIdx.x;
    if (i < n) { float v = f2[i]; F2[i] = v; F2b[i] = 0.2f * v; }
}

// ---------------- NEW: main attention, 192 rows x 6 waves, dbuf gl16, grid 256 ----------------
__global__ __launch_bounds__(384, 1) void attn_main(
    const unsigned short* __restrict__ Ht,
    const unsigned long long* __restrict__ mask,
    const float* __restrict__ RA, const float* __restrict__ RB,
    const float* __restrict__ F2, const float* __restrict__ F2b,
    unsigned short* __restrict__ x2)
{
    __shared__ __align__(16) unsigned short htile[2 * HID * 64];   // 64 KB dbuf, swizzled [256][64]
    const int w = threadIdx.x >> 6, l = threadIdx.x & 63;
    const int lrow = l & 31, kh = l >> 5;
    const int h = blockIdx.y;
    const int rowbase = blockIdx.x * 192;
    const int myrow = rowbase + w * 32 + lrow;
    const bool wactive = (rowbase + w * 32) < NPAD;
    const bool act = wactive && (myrow < NN);
    const unsigned short* Hh = Ht + (size_t)h * HID * NPAD;
    const float* F2h = F2 + (size_t)h * NPAD;
    const float* F2bh = F2b + (size_t)h * NPAD;
    float ra = 0.f, rb = 0.f;
    if (wactive) { ra = RA[(size_t)h * NPAD + myrow]; rb = RB[(size_t)h * NPAD + myrow]; }
    const int srcc = (l & 7) ^ (l >> 3);
    float dsum = 0.f;
    f32x16 acc[8];
#pragma unroll
    for (int i = 0; i < 8; ++i) acc[i] = (f32x16)0.0f;

    auto STAGE = [&](int b, int jb) {
        for (int c = w; c < 32; c += 6) {
            int f = c * 8 + (l >> 3);
            gl16(Hh + (size_t)f * NPAD + jb * 64 + srcc * 8, (char*)htile + b * 32768 + c * 1024);
        }
    };
    STAGE(0, 0);
    __syncthreads();           // implicit vmcnt(0): buf0 ready
    int cur = 0;
#pragma unroll 1
    for (int jb = 0; jb < NPAD / 64; ++jb) {
        if (jb + 1 < NPAD / 64) STAGE(cur ^ 1, jb + 1);   // async prefetch next tile
        if (wactive) {
            unsigned long long mword = act ? mask[(size_t)myrow * MSTR + jb] : 0ull;
            const char* tb = (const char*)htile + cur * 32768;
#pragma unroll
            for (int kk = 0; kk < 4; ++kk) {
                unsigned int mbyte = (unsigned int)((mword >> (kk * 16 + kh * 8)) & 0xffull);
                int j0 = jb * 64 + kk * 16 + kh * 8;
                f32x4 fa0 = *(const f32x4*)(F2h + j0);
                f32x4 fa1 = *(const f32x4*)(F2h + j0 + 4);
                f32x4 fb0 = *(const f32x4*)(F2bh + j0);
                f32x4 fb1 = *(const f32x4*)(F2bh + j0 + 4);
                float p[8];
#pragma unroll
                for (int e = 0; e < 8; ++e) {
                    float fe = (e < 4) ? fa0[e & 3] : fa1[e & 3];
                    float fb = (e < 4) ? fb0[e & 3] : fb1[e & 3];
                    float pe = __expf(fmaxf(ra + fe, rb + fb));
                    p[e] = (mbyte & (1u << e)) ? pe : 0.f;
                }
                // truncating bf16 pack (v_perm) + denominator summed over the SAME truncated values
                union { unsigned int u[4]; short8 s8; } cv;
#pragma unroll
                for (int q = 0; q < 4; ++q) {
                    unsigned int up = __builtin_amdgcn_perm(__float_as_uint(p[2 * q + 1]),
                                                            __float_as_uint(p[2 * q]), 0x07060302u);
                    cv.u[q] = up;
                    dsum += __uint_as_float(up << 16);
                    dsum += __uint_as_float(up & 0xffff0000u);
                }
#pragma unroll
                for (int ft = 0; ft < 8; ++ft) {
                    int fr = ft * 32 + lrow;
                    short8 bfrag = *(const short8*)(tb + fr * 128 + (((kk * 2 + kh) * 16) ^ ((fr & 7) << 4)));
                    acc[ft] = __builtin_amdgcn_mfma_f32_32x32x16_bf16(cv.s8, bfrag, acc[ft], 0, 0, 0);
                }
            }
        }
        __syncthreads();       // implicit vmcnt(0): next tile landed; all reads of cur done
        cur ^= 1;
    }

    if (!wactive) return;
    dsum += __shfl_xor(dsum, 32);
    float dinv = (dsum > 0.f) ? (1.0f / dsum) : 0.f;
    float rcp16[16];
#pragma unroll
    for (int g = 0; g < 4; ++g)
#pragma unroll
        for (int rr = 0; rr < 4; ++rr)
            rcp16[g * 4 + rr] = __shfl(dinv, (g << 3) + (kh << 2) + rr);

    // normalize + ELU -> direct bf16 stores (2x64B segments per wave-store)
#pragma unroll
    for (int ft = 0; ft < 8; ++ft)
#pragma unroll
        for (int g = 0; g < 4; ++g)
#pragma unroll
            for (int rr = 0; rr < 4; ++rr) {
                int grow = rowbase + w * 32 + (g << 3) + (kh << 2) + rr;
                if (grow < NN) {
                    float v = acc[ft][g * 4 + rr] * rcp16[g * 4 + rr];
                    v = (v > 0.f) ? v : (__expf(v) - 1.f);
                    x2[(size_t)grow * FTOT + h * HID + ft * 32 + lrow] = f2bf(v);
                }
            }
}

// ---------------- GEMM2 (round-1 verified): hct[c][i] = sum_k Wc[k][c] x2[i][k] ----------------
__global__ __launch_bounds__(256, 2) void gemm_hc(const unsigned short* __restrict__ A,
                                                  const unsigned short* __restrict__ B,
                                                  unsigned short* __restrict__ hct) {
    int w = threadIdx.x >> 6, l = threadIdx.x & 63;
    int lrow = l & 31, kh = l >> 5;
    int nbase = blockIdx.x * 128 + w * 32;
    int brow = nbase + lrow; if (brow > NN - 1) brow = NN - 1;
    f32x16 acc = (f32x16)0.0f;
    const short8* ap = (const short8*)(A + (size_t)lrow * FTOT + kh * 8);
    const short8* bp = (const short8*)(B + (size_t)brow * FTOT + kh * 8);
    for (int kk = 0; kk < FTOT / 16; ++kk) {
        short8 af = ap[kk * 2];
        short8 bf = bp[kk * 2];
        acc = __builtin_amdgcn_mfma_f32_32x32x16_bf16(af, bf, acc, 0, 0, 0);
    }
    int i = nbase + lrow;
#pragma unroll
    for (int g = 0; g < 4; ++g) {
        int c0 = (g << 3) + (kh << 2);
#pragma unroll
        for (int r = 0; r < 4; ++r)
            hct[(size_t)(c0 + r) * NPAD + i] = f2bf(acc[g * 4 + r]);
    }
}

// ---------------- NEW: classifier attention, j-split 4 ways, partials ----------------
__global__ __launch_bounds__(256, 2) void cls_part(
    const unsigned short* __restrict__ hctb,
    const unsigned long long* __restrict__ mask,
    const float* __restrict__ RAc, const float* __restrict__ RBc,
    const float* __restrict__ F2c, const float* __restrict__ F2cb,
    float* __restrict__ pacc, float* __restrict__ pdsum)
{
    __shared__ __align__(16) unsigned short ctile[2 * NC * 64];   // 8 KB dbuf
    const int w = threadIdx.x >> 6, l = threadIdx.x & 63;
    const int lrow = l & 31, kh = l >> 5;
    const int q = blockIdx.y;
    const int rowbase = blockIdx.x * 128;
    const int myrow = rowbase + w * 32 + lrow;
    const bool act = myrow < NN;
    float ra = RAc[myrow], rb = RBc[myrow];
    const int srcc = (l & 7) ^ (l >> 3);
    const int JB0 = q * 24, JB1 = (JB0 + 24 < NPAD / 64) ? JB0 + 24 : NPAD / 64;
    float dsum = 0.f;
    f32x16 acc = (f32x16)0.0f;

    auto STAGE = [&](int b, int jb) {
        int f = w * 8 + (l >> 3);
        gl16(hctb + (size_t)f * NPAD + jb * 64 + srcc * 8, (char*)ctile + b * 4096 + w * 1024);
    };
    STAGE(0, JB0);
    __syncthreads();
    int cur = 0;
#pragma unroll 1
    for (int jb = JB0; jb < JB1; ++jb) {
        if (jb + 1 < JB1) STAGE(cur ^ 1, jb + 1);
        {
            unsigned long long mword = act ? mask[(size_t)myrow * MSTR + jb] : 0ull;
            const char* tb = (const char*)ctile + cur * 4096;
#pragma unroll
            for (int kk = 0; kk < 4; ++kk) {
                unsigned int mbyte = (unsigned int)((mword >> (kk * 16 + kh * 8)) & 0xffull);
                int j0 = jb * 64 + kk * 16 + kh * 8;
                f32x4 fa0 = *(const f32x4*)(F2c + j0);
                f32x4 fa1 = *(const f32x4*)(F2c + j0 + 4);
                f32x4 fb0 = *(const f32x4*)(F2cb + j0);
                f32x4 fb1 = *(const f32x4*)(F2cb + j0 + 4);
                float p[8];
#pragma unroll
                for (int e = 0; e < 8; ++e) {
                    float fe = (e < 4) ? fa0[e & 3] : fa1[e & 3];
                    float fb = (e < 4) ? fb0[e & 3] : fb1[e & 3];
                    float pe = __expf(fmaxf(ra + fe, rb + fb));
                    p[e] = (mbyte & (1u << e)) ? pe : 0.f;
                }
                union { unsigned int u[4]; short8 s8; } cv;
#pragma unroll
                for (int t = 0; t < 4; ++t) {
                    unsigned int up = __builtin_amdgcn_perm(__float_as_uint(p[2 * t + 1]),
                                                            __float_as_uint(p[2 * t]), 0x07060302u);
                    cv.u[t] = up;
                    dsum += __uint_as_float(up << 16);
                    dsum += __uint_as_float(up & 0xffff0000u);
                }
                short8 bfrag = *(const short8*)(tb + lrow * 128 + (((kk * 2 + kh) * 16) ^ ((lrow & 7) << 4)));
                acc = __builtin_amdgcn_mfma_f32_32x32x16_bf16(cv.s8, bfrag, acc, 0, 0, 0);
            }
        }
        __syncthreads();
        cur ^= 1;
    }
    dsum += __shfl_xor(dsum, 32);
    if (kh == 0) pdsum[(size_t)q * NPAD + myrow] = dsum;
#pragma unroll
    for (int g = 0; g < 4; ++g)
#pragma unroll
        for (int rr = 0; rr < 4; ++rr) {
            int i = rowbase + w * 32 + (g << 3) + (kh << 2) + rr;
            pacc[((size_t)q * NPAD + i) * NC + lrow] = acc[g * 4 + rr];
        }
}

__global__ void cls_merge(const float* __restrict__ pacc, const float* __restrict__ pdsum,
                          float* __restrict__ outp) {
    int i = blockIdx.x * 8 + (threadIdx.x >> 5);
    int c = threadIdx.x & 31;
    if (i >= NN) return;
    float num = 0.f, den = 0.f;
#pragma unroll
    for (int q = 0; q < 4; ++q) {
        num += pacc[((size_t)q * NPAD + i) * NC + c];
        den += pdsum[(size_t)q * NPAD + i];
    }
    outp[(size_t)i * NC + c] = (den > 0.f) ? num / den : 0.f;
}

// ---------------- launcher ----------------
extern "C" void kernel_launch(void* const* d_in, const int* in_sizes, int n_in,
                              void* d_out, int out_size, void* d_ws, size_t ws_size,
                              hipStream_t stream) {
    const float* features = (const float*)d_in[0];
    const int*   adj      = (const int*)d_in[1];
    const float* W0       = (const float*)d_in[2];
    const float* a10      = (const float*)d_in[3];
    const float* a20      = (const float*)d_in[4];
    const float* Wc       = (const float*)d_in[5];
    const float* a1c      = (const float*)d_in[6];
    const float* a2c      = (const float*)d_in[7];
    float* out = (float*)d_out;

    char* p = (char*)d_ws;
    auto alloc = [&](size_t bytes) { char* r = p; p += (bytes + 255) & ~(size_t)255; return r; };
    unsigned long long* mask = (unsigned long long*)alloc((size_t)NN * MSTR * 8);
    unsigned short* Xbf = (unsigned short*)alloc((size_t)NN * DF * 2);
    unsigned short* Wt  = (unsigned short*)alloc((size_t)FTOT * DF * 2);
    unsigned short* Ht  = (unsigned short*)alloc((size_t)FTOT * NPAD * 2);
    unsigned short* x2  = (unsigned short*)alloc((size_t)NN * FTOT * 2);
    unsigned short* Wct = (unsigned short*)alloc((size_t)NC * FTOT * 2);
    unsigned short* hct = (unsigned short*)alloc((size_t)NC * NPAD * 2);
    float* f1  = (float*)alloc((size_t)NH * NPAD * 4);
    float* f2  = (float*)alloc((size_t)NH * NPAD * 4);
    float* RA  = (float*)alloc((size_t)NH * NPAD * 4);
    float* RB  = (float*)alloc((size_t)NH * NPAD * 4);
    float* F2  = (float*)alloc((size_t)NH * NPAD * 4);
    float* F2b = (float*)alloc((size_t)NH * NPAD * 4);
    float* f1c  = (float*)alloc((size_t)NPAD * 4);
    float* f2c  = (float*)alloc((size_t)NPAD * 4);
    float* RAc  = (float*)alloc((size_t)NPAD * 4);
    float* RBc  = (float*)alloc((size_t)NPAD * 4);
    float* F2c  = (float*)alloc((size_t)NPAD * 4);
    float* F2cb = (float*)alloc((size_t)NPAD * 4);
    // classifier partials overlay Xbf (dead after gemm_h): 3.2 MB <= 6.1 MB
    float* pacc  = (float*)Xbf;
    float* pdsum = pacc + (size_t)4 * NPAD * NC;

    pack_bits<<<dim3(3, NN), 256, 0, stream>>>(adj, (unsigned char*)mask);
    cast_x4<<<(NN * DF / 4 + 255) / 256, 256, 0, stream>>>(features, Xbf, NN * DF / 4);
    wt_pack<<<FTOT, 256, 0, stream>>>(W0, Wt);
    wct_pack<<<NC, 256, 0, stream>>>(Wc, Wct);

    gemm_h<<<dim3(NPAD / 128, FTOT / 128), 256, 0, stream>>>(Xbf, Wt, Ht);
    f12_kern<<<dim3((NPAD + 255) / 256, NH), 256, 0, stream>>>(Ht, a10, a20, f1, f2, HID);
    prep_rows<<<dim3(94, NH), 256, 0, stream>>>(mask, f1, f2, RA, RB);
    prep_f2s<<<(NH * NPAD + 255) / 256, 256, 0, stream>>>(f2, F2, F2b, NH * NPAD);

    attn_main<<<dim3(32, NH), 384, 0, stream>>>(Ht, mask, RA, RB, F2, F2b, x2);

    gemm_hc<<<NPAD / 128, 256, 0, stream>>>(Wct, x2, hct);
    f12_kern<<<dim3((NPAD + 255) / 256, 1), 256, 0, stream>>>(hct, a1c, a2c, f1c, f2c, NC);
    prep_rows<<<dim3(94, 1), 256, 0, stream>>>(mask, f1c, f2c, RAc, RBc);
    prep_f2s<<<(NPAD + 255) / 256, 256, 0, stream>>>(f2c, F2c, F2cb, NPAD);

    cls_part<<<dim3(47, 4), 256, 0, stream>>>(hct, mask, RAc, RBc, F2c, F2cb, pacc, pdsum);
    cls_merge<<<750, 256, 0, stream>>>(pacc, pdsum, out);
}

// Round 5
// 678.264 us; speedup vs baseline: 1.6662x; 1.3939x over previous
//
#include <hip/hip_runtime.h>
#include <hip/hip_bf16.h>

#define NN 6000
#define NPAD 6016      // 94*64
#define DF 512
#define HID 256
#define NH 8
#define NC 32
#define FTOT 2048
#define MSTR 96        // u64 words per mask row
#define NJB (NPAD / 64)

using short8 = __attribute__((ext_vector_type(8))) short;
using f32x16 = __attribute__((ext_vector_type(16))) float;
using f32x4  = __attribute__((ext_vector_type(4))) float;

__device__ __forceinline__ unsigned short f2bf(float f) {
    unsigned int u = __float_as_uint(f);
    return (unsigned short)((u + 0x7fffu + ((u >> 16) & 1u)) >> 16);
}
__device__ __forceinline__ float bf2f(unsigned short s) {
    return __uint_as_float(((unsigned int)s) << 16);
}
// async global->LDS, 16B per lane; LDS dest = wave-uniform base + lane*16
__device__ __forceinline__ void gl16(const void* g, void* l) {
    __builtin_amdgcn_global_load_lds(
        (const __attribute__((address_space(1))) unsigned int*)g,
        (__attribute__((address_space(3))) unsigned int*)l, 16, 0, 0);
}

// ---------------- prep kernels (verified r3/r4) ----------------

__global__ void pack_bits(const int* __restrict__ adj, unsigned char* __restrict__ maskb) {
    int row = blockIdx.y;
    int b = blockIdx.x * 256 + threadIdx.x;     // byte index 0..767
    if (b >= 768) return;
    int j0 = b * 8;
    unsigned int v = 0;
    if (j0 + 7 < NN) {
        const int4* p = (const int4*)(adj + (size_t)row * NN + j0);
        int4 a = p[0], c = p[1];
        v = (unsigned)((a.x>0) | ((a.y>0)<<1) | ((a.z>0)<<2) | ((a.w>0)<<3)
          | ((c.x>0)<<4) | ((c.y>0)<<5) | ((c.z>0)<<6) | ((c.w>0)<<7));
    }
    maskb[(size_t)row * 768 + b] = (unsigned char)v;
}

__global__ void cast_x4(const float* __restrict__ x, unsigned short* __restrict__ xb, int n4) {
    int i = blockIdx.x * 256 + threadIdx.x;
    if (i >= n4) return;
    float4 v = ((const float4*)x)[i];
    unsigned long long pk = (unsigned long long)f2bf(v.x)
        | ((unsigned long long)f2bf(v.y) << 16)
        | ((unsigned long long)f2bf(v.z) << 32)
        | ((unsigned long long)f2bf(v.w) << 48);
    ((unsigned long long*)xb)[i] = pk;
}

__global__ void wt_pack(const float* __restrict__ W0, unsigned short* __restrict__ Wt) {
    int fp = blockIdx.x;                 // h*256+f
    int h = fp >> 8, f = fp & 255;
    for (int k = threadIdx.x; k < DF; k += 256)
        Wt[(size_t)fp * DF + k] = f2bf(W0[(((size_t)h * DF + k) << 8) | f]);
}

__global__ void wct_pack(const float* __restrict__ Wc, unsigned short* __restrict__ Wct) {
    int c = blockIdx.x;
    for (int k = threadIdx.x; k < FTOT; k += 256)
        Wct[(size_t)c * FTOT + k] = f2bf(Wc[(size_t)k * NC + c]);
}

// ---------------- GEMM1 (verified r3): Ht[f][i] = sum_k X[i][k] W[k][f] ----------------
__global__ __launch_bounds__(256, 2) void gemm_h(const unsigned short* __restrict__ A,
                                                 const unsigned short* __restrict__ B,
                                                 unsigned short* __restrict__ Ht) {
    __shared__ __align__(16) unsigned short As[128 * 64];
    __shared__ __align__(16) unsigned short Bs[128 * 64];
    const int w = threadIdx.x >> 6, l = threadIdx.x & 63;
    const int lrow = l & 31, kh = l >> 5;
    const int wm = w >> 1, wn = w & 1;
    const int mbase = blockIdx.x * 128, nbase = blockIdx.y * 128;
    const int srcc = (l & 7) ^ (l >> 3);
    f32x16 acc[2][2];
#pragma unroll
    for (int i = 0; i < 2; ++i)
#pragma unroll
        for (int j = 0; j < 2; ++j) acc[i][j] = (f32x16)0.0f;

#pragma unroll 1
    for (int kb = 0; kb < DF / 64; ++kb) {
        __syncthreads();
#pragma unroll
        for (int q = 0; q < 4; ++q) {
            int c = q * 4 + w;
            int r = c * 8 + (l >> 3);
            int arow = mbase + r; if (arow > NN - 1) arow = NN - 1;
            gl16(A + (size_t)arow * DF + kb * 64 + srcc * 8, (char*)As + c * 1024);
            gl16(B + (size_t)(nbase + r) * DF + kb * 64 + srcc * 8, (char*)Bs + c * 1024);
        }
        __syncthreads();
#pragma unroll
        for (int kk = 0; kk < 4; ++kk) {
            short8 av[2], bv[2];
#pragma unroll
            for (int mt = 0; mt < 2; ++mt) {
                int r = wm * 64 + mt * 32 + lrow;
                av[mt] = *(const short8*)((const char*)As + r * 128 + ((((kk << 1) | kh) ^ (r & 7)) << 4));
            }
#pragma unroll
            for (int ft = 0; ft < 2; ++ft) {
                int r = wn * 64 + ft * 32 + lrow;
                bv[ft] = *(const short8*)((const char*)Bs + r * 128 + ((((kk << 1) | kh) ^ (r & 7)) << 4));
            }
#pragma unroll
            for (int mt = 0; mt < 2; ++mt)
#pragma unroll
                for (int ft = 0; ft < 2; ++ft)
                    acc[mt][ft] = __builtin_amdgcn_mfma_f32_32x32x16_bf16(av[mt], bv[ft], acc[mt][ft], 0, 0, 0);
        }
    }
#pragma unroll
    for (int mt = 0; mt < 2; ++mt)
#pragma unroll
        for (int ft = 0; ft < 2; ++ft) {
            size_t n = nbase + wn * 64 + ft * 32 + lrow;
#pragma unroll
            for (int g = 0; g < 4; ++g) {
                int m0 = mbase + wm * 64 + mt * 32 + (g << 3) + (kh << 2);
                unsigned long long pk =
                    (unsigned long long)f2bf(acc[mt][ft][g * 4 + 0]) |
                    ((unsigned long long)f2bf(acc[mt][ft][g * 4 + 1]) << 16) |
                    ((unsigned long long)f2bf(acc[mt][ft][g * 4 + 2]) << 32) |
                    ((unsigned long long)f2bf(acc[mt][ft][g * 4 + 3]) << 48);
                *(unsigned long long*)(Ht + n * NPAD + m0) = pk;
            }
        }
}

// ---------------- f1/f2 (verified) ----------------
__global__ void f12_kern(const unsigned short* __restrict__ Ht, const float* __restrict__ a1,
                         const float* __restrict__ a2, float* __restrict__ f1, float* __restrict__ f2,
                         int fdim) {
    int h = blockIdx.y;
    int i = blockIdx.x * 256 + threadIdx.x;
    if (i >= NPAD) return;
    float s1 = 0.f, s2 = 0.f;
    const unsigned short* base = Ht + (size_t)h * fdim * NPAD + i;
    for (int f = 0; f < fdim; ++f) {
        float v = bf2f(base[(size_t)f * NPAD]);
        s1 = fmaf(v, a1[h * fdim + f], s1);
        s2 = fmaf(v, a2[h * fdim + f], s2);
    }
    f1[(size_t)h * NPAD + i] = s1;
    f2[(size_t)h * NPAD + i] = s2;
}

// ---------------- NEW: per-head GLOBAL max -> RA/RB (replaces masked prep_rows) ----------------
// M_i = lrelu(f1_i + max_j f2_j) >= lrelu(f1_i + f2_j) for all j (lrelu monotone).
// Softmax ratio invariant to the bound; exp args stay in [-~9, 0] (no over/underflow).
__global__ void rarb_kern(const float* __restrict__ f1all, const float* __restrict__ f2all,
                          float* __restrict__ RA, float* __restrict__ RB) {
    int h = blockIdx.x;
    __shared__ float red[8];
    const float* f2h = f2all + (size_t)h * NPAD;
    float m = -3.0e38f;
    for (int i = threadIdx.x; i < NN; i += 256) m = fmaxf(m, f2h[i]);
    for (int off = 32; off; off >>= 1) m = fmaxf(m, __shfl_xor(m, off));
    if ((threadIdx.x & 63) == 0) red[threadIdx.x >> 6] = m;
    __syncthreads();
    if (threadIdx.x == 0)
        red[4] = fmaxf(fmaxf(red[0], red[1]), fmaxf(red[2], red[3]));
    __syncthreads();
    float Mh = red[4];
    for (int i = threadIdx.x; i < NPAD; i += 256) {
        float F1 = (i < NN) ? f1all[(size_t)h * NPAD + i] : 0.f;
        float t2 = F1 + Mh;
        float Mi = fmaxf(t2, 0.2f * t2);
        RA[(size_t)h * NPAD + i] = F1 - Mi;
        RB[(size_t)h * NPAD + i] = 0.2f * F1 - Mi;
    }
}

// ---------------- main attention: 96 rows x 3 waves, dbuf gl16, grid 504 (~2/CU) ----------------
__global__ __launch_bounds__(192, 1) void attn_main(
    const unsigned short* __restrict__ Ht,
    const unsigned long long* __restrict__ mask,
    const float* __restrict__ RA, const float* __restrict__ RB,
    const float* __restrict__ F2,
    unsigned short* __restrict__ x2)
{
    __shared__ __align__(16) unsigned short htile[2 * HID * 64];   // 64 KB dbuf, swizzled [256][64]
    const int w = threadIdx.x >> 6, l = threadIdx.x & 63;
    const int lrow = l & 31, kh = l >> 5;
    const int h = blockIdx.y;
    const int rowbase = blockIdx.x * 96;
    const int myrow = rowbase + w * 32 + lrow;
    const bool wactive = (rowbase + w * 32) < NPAD;
    const bool act = wactive && (myrow < NN);
    const unsigned short* Hh = Ht + (size_t)h * HID * NPAD;
    const float* F2h = F2 + (size_t)h * NPAD;
    float ra = 0.f, rb = 0.f;
    if (wactive) { ra = RA[(size_t)h * NPAD + myrow]; rb = RB[(size_t)h * NPAD + myrow]; }
    const int srcc = (l & 7) ^ (l >> 3);
    float dsum = 0.f;
    f32x16 acc[8];
#pragma unroll
    for (int i = 0; i < 8; ++i) acc[i] = (f32x16)0.0f;

    auto STAGE = [&](int b, int jb) {
        for (int c = w; c < 32; c += 3) {
            int f = c * 8 + (l >> 3);
            gl16(Hh + (size_t)f * NPAD + jb * 64 + srcc * 8, (char*)htile + b * 32768 + c * 1024);
        }
    };
    STAGE(0, 0);
    __syncthreads();           // implicit vmcnt(0): buf0 ready
    unsigned long long mw = act ? mask[(size_t)myrow * MSTR] : 0ull;
    int cur = 0;
#pragma unroll 1
    for (int jb = 0; jb < NJB; ++jb) {
        if (jb + 1 < NJB) STAGE(cur ^ 1, jb + 1);   // async prefetch next tile
        unsigned long long mw_n = (act && jb + 1 < NJB) ? mask[(size_t)myrow * MSTR + jb + 1] : 0ull;
        if (wactive) {
            const char* tb = (const char*)htile + cur * 32768;
#pragma unroll
            for (int kk = 0; kk < 4; ++kk) {
                unsigned int mbyte = (unsigned int)((mw >> (kk * 16 + kh * 8)) & 0xffull);
                int j0 = jb * 64 + kk * 16 + kh * 8;
                f32x4 fa0 = *(const f32x4*)(F2h + j0);
                f32x4 fa1 = *(const f32x4*)(F2h + j0 + 4);
                float p[8];
#pragma unroll
                for (int e = 0; e < 8; ++e) {
                    float fe = (e < 4) ? fa0[e & 3] : fa1[e & 3];
                    float pe = __expf(fmaxf(ra + fe, rb + 0.2f * fe));
                    p[e] = (mbyte & (1u << e)) ? pe : 0.f;
                }
                // truncating bf16 pack; denominator summed over the SAME truncated values (r4-verified)
                union { unsigned int u[4]; short8 s8; } cv;
#pragma unroll
                for (int q = 0; q < 4; ++q) {
                    unsigned int up = __builtin_amdgcn_perm(__float_as_uint(p[2 * q + 1]),
                                                            __float_as_uint(p[2 * q]), 0x07060302u);
                    cv.u[q] = up;
                    dsum += __uint_as_float(up << 16);
                    dsum += __uint_as_float(up & 0xffff0000u);
                }
                __builtin_amdgcn_s_setprio(1);
#pragma unroll
                for (int ft = 0; ft < 8; ++ft) {
                    int fr = ft * 32 + lrow;
                    short8 bfrag = *(const short8*)(tb + fr * 128 + (((kk * 2 + kh) * 16) ^ ((fr & 7) << 4)));
                    acc[ft] = __builtin_amdgcn_mfma_f32_32x32x16_bf16(cv.s8, bfrag, acc[ft], 0, 0, 0);
                }
                __builtin_amdgcn_s_setprio(0);
            }
        }
        __syncthreads();       // implicit vmcnt(0): next tile landed; all reads of cur done
        cur ^= 1;
        mw = mw_n;
    }

    if (!wactive) return;
    dsum += __shfl_xor(dsum, 32);
    float dinv = (dsum > 0.f) ? (1.0f / dsum) : 0.f;
    float rcp16[16];
#pragma unroll
    for (int g = 0; g < 4; ++g)
#pragma unroll
        for (int rr = 0; rr < 4; ++rr)
            rcp16[g * 4 + rr] = __shfl(dinv, (g << 3) + (kh << 2) + rr);

#pragma unroll
    for (int ft = 0; ft < 8; ++ft)
#pragma unroll
        for (int g = 0; g < 4; ++g)
#pragma unroll
            for (int rr = 0; rr < 4; ++rr) {
                int grow = rowbase + w * 32 + (g << 3) + (kh << 2) + rr;
                if (grow < NN) {
                    float v = acc[ft][g * 4 + rr] * rcp16[g * 4 + rr];
                    v = (v > 0.f) ? v : (__expf(v) - 1.f);
                    x2[(size_t)grow * FTOT + h * HID + ft * 32 + lrow] = f2bf(v);
                }
            }
}

// ---------------- GEMM2 v2: split-K x8 -> f32 partials ----------------
__global__ __launch_bounds__(256, 2) void gemm_hc(const unsigned short* __restrict__ A,  // Wct [32][2048]
                                                  const unsigned short* __restrict__ B,  // x2 [6000][2048]
                                                  float* __restrict__ pk) {              // [8][32][NPAD]
    int w = threadIdx.x >> 6, l = threadIdx.x & 63;
    int lrow = l & 31, kh = l >> 5;
    int q = blockIdx.y;
    int nbase = blockIdx.x * 128 + w * 32;
    int brow = nbase + lrow; if (brow > NN - 1) brow = NN - 1;
    f32x16 acc = (f32x16)0.0f;
    const short8* ap = (const short8*)(A + (size_t)lrow * FTOT + q * 256 + kh * 8);
    const short8* bp = (const short8*)(B + (size_t)brow * FTOT + q * 256 + kh * 8);
#pragma unroll
    for (int kk = 0; kk < 16; ++kk) {
        short8 af = ap[kk * 2];
        short8 bf = bp[kk * 2];
        acc = __builtin_amdgcn_mfma_f32_32x32x16_bf16(af, bf, acc, 0, 0, 0);
    }
    int i = nbase + lrow;
#pragma unroll
    for (int g = 0; g < 4; ++g) {
        int c0 = (g << 3) + (kh << 2);
#pragma unroll
        for (int r = 0; r < 4; ++r)
            pk[((size_t)q * NC + c0 + r) * NPAD + i] = acc[g * 4 + r];
    }
}

__global__ void merge_hc(const float* __restrict__ pk, unsigned short* __restrict__ hct) {
    int i = blockIdx.x * 256 + threadIdx.x;
    int c = blockIdx.y;
    if (i >= NPAD) return;
    float s = 0.f;
#pragma unroll
    for (int q = 0; q < 8; ++q) s += pk[((size_t)q * NC + c) * NPAD + i];
    hct[(size_t)c * NPAD + i] = f2bf(s);
}

// ---------------- classifier attention (r4-verified, F2b folded) ----------------
__global__ __launch_bounds__(256, 2) void cls_part(
    const unsigned short* __restrict__ hctb,
    const unsigned long long* __restrict__ mask,
    const float* __restrict__ RAc, const float* __restrict__ RBc,
    const float* __restrict__ F2c,
    float* __restrict__ pacc, float* __restrict__ pdsum)
{
    __shared__ __align__(16) unsigned short ctile[2 * NC * 64];   // 8 KB dbuf
    const int w = threadIdx.x >> 6, l = threadIdx.x & 63;
    const int lrow = l & 31, kh = l >> 5;
    const int q = blockIdx.y;
    const int rowbase = blockIdx.x * 128;
    const int myrow = rowbase + w * 32 + lrow;
    const bool act = myrow < NN;
    float ra = RAc[myrow], rb = RBc[myrow];
    const int srcc = (l & 7) ^ (l >> 3);
    const int JB0 = q * 24, JB1 = (JB0 + 24 < NJB) ? JB0 + 24 : NJB;
    float dsum = 0.f;
    f32x16 acc = (f32x16)0.0f;

    auto STAGE = [&](int b, int jb) {
        int f = w * 8 + (l >> 3);
        gl16(hctb + (size_t)f * NPAD + jb * 64 + srcc * 8, (char*)ctile + b * 4096 + w * 1024);
    };
    STAGE(0, JB0);
    __syncthreads();
    int cur = 0;
#pragma unroll 1
    for (int jb = JB0; jb < JB1; ++jb) {
        if (jb + 1 < JB1) STAGE(cur ^ 1, jb + 1);
        {
            unsigned long long mword = act ? mask[(size_t)myrow * MSTR + jb] : 0ull;
            const char* tb = (const char*)ctile + cur * 4096;
#pragma unroll
            for (int kk = 0; kk < 4; ++kk) {
                unsigned int mbyte = (unsigned int)((mword >> (kk * 16 + kh * 8)) & 0xffull);
                int j0 = jb * 64 + kk * 16 + kh * 8;
                f32x4 fa0 = *(const f32x4*)(F2c + j0);
                f32x4 fa1 = *(const f32x4*)(F2c + j0 + 4);
                float p[8];
#pragma unroll
                for (int e = 0; e < 8; ++e) {
                    float fe = (e < 4) ? fa0[e & 3] : fa1[e & 3];
                    float pe = __expf(fmaxf(ra + fe, rb + 0.2f * fe));
                    p[e] = (mbyte & (1u << e)) ? pe : 0.f;
                }
                union { unsigned int u[4]; short8 s8; } cv;
#pragma unroll
                for (int t = 0; t < 4; ++t) {
                    unsigned int up = __builtin_amdgcn_perm(__float_as_uint(p[2 * t + 1]),
                                                            __float_as_uint(p[2 * t]), 0x07060302u);
                    cv.u[t] = up;
                    dsum += __uint_as_float(up << 16);
                    dsum += __uint_as_float(up & 0xffff0000u);
                }
                short8 bfrag = *(const short8*)(tb + lrow * 128 + (((kk * 2 + kh) * 16) ^ ((lrow & 7) << 4)));
                acc = __builtin_amdgcn_mfma_f32_32x32x16_bf16(cv.s8, bfrag, acc, 0, 0, 0);
            }
        }
        __syncthreads();
        cur ^= 1;
    }
    dsum += __shfl_xor(dsum, 32);
    if (kh == 0) pdsum[(size_t)q * NPAD + myrow] = dsum;
#pragma unroll
    for (int g = 0; g < 4; ++g)
#pragma unroll
        for (int rr = 0; rr < 4; ++rr) {
            int i = rowbase + w * 32 + (g << 3) + (kh << 2) + rr;
            pacc[((size_t)q * NPAD + i) * NC + lrow] = acc[g * 4 + rr];
        }
}

__global__ void cls_merge(const float* __restrict__ pacc, const float* __restrict__ pdsum,
                          float* __restrict__ outp) {
    int i = blockIdx.x * 8 + (threadIdx.x >> 5);
    int c = threadIdx.x & 31;
    if (i >= NN) return;
    float num = 0.f, den = 0.f;
#pragma unroll
    for (int q = 0; q < 4; ++q) {
        num += pacc[((size_t)q * NPAD + i) * NC + c];
        den += pdsum[(size_t)q * NPAD + i];
    }
    outp[(size_t)i * NC + c] = (den > 0.f) ? num / den : 0.f;
}

// ---------------- launcher ----------------
extern "C" void kernel_launch(void* const* d_in, const int* in_sizes, int n_in,
                              void* d_out, int out_size, void* d_ws, size_t ws_size,
                              hipStream_t stream) {
    const float* features = (const float*)d_in[0];
    const int*   adj      = (const int*)d_in[1];
    const float* W0       = (const float*)d_in[2];
    const float* a10      = (const float*)d_in[3];
    const float* a20      = (const float*)d_in[4];
    const float* Wc       = (const float*)d_in[5];
    const float* a1c      = (const float*)d_in[6];
    const float* a2c      = (const float*)d_in[7];
    float* out = (float*)d_out;

    char* p = (char*)d_ws;
    auto alloc = [&](size_t bytes) { char* r = p; p += (bytes + 255) & ~(size_t)255; return r; };
    unsigned long long* mask = (unsigned long long*)alloc((size_t)NN * MSTR * 8);
    unsigned short* Xbf = (unsigned short*)alloc((size_t)NN * DF * 2);
    unsigned short* Wt  = (unsigned short*)alloc((size_t)FTOT * DF * 2);
    unsigned short* Ht  = (unsigned short*)alloc((size_t)FTOT * NPAD * 2);
    unsigned short* x2  = (unsigned short*)alloc((size_t)NN * FTOT * 2);
    unsigned short* Wct = (unsigned short*)alloc((size_t)NC * FTOT * 2);
    unsigned short* hct = (unsigned short*)alloc((size_t)NC * NPAD * 2);
    float* f1  = (float*)alloc((size_t)NH * NPAD * 4);
    float* f2  = (float*)alloc((size_t)NH * NPAD * 4);
    float* RA  = (float*)alloc((size_t)NH * NPAD * 4);
    float* RB  = (float*)alloc((size_t)NH * NPAD * 4);
    float* f1c  = (float*)alloc((size_t)NPAD * 4);
    float* f2c  = (float*)alloc((size_t)NPAD * 4);
    float* RAc  = (float*)alloc((size_t)NPAD * 4);
    float* RBc  = (float*)alloc((size_t)NPAD * 4);
    // overlays on dead regions:
    //   pkhc (8*32*NPAD f32 = 6.16 MB) on Xbf+Wt (8.25 MB, dead after gemm_h)
    //   pacc/pdsum (cls partials, 3.2 MB) on same region, used after merge_hc consumed pkhc
    float* pkhc  = (float*)Xbf;
    float* pacc  = (float*)Xbf;
    float* pdsum = pacc + (size_t)4 * NPAD * NC;

    pack_bits<<<dim3(3, NN), 256, 0, stream>>>(adj, (unsigned char*)mask);
    cast_x4<<<(NN * DF / 4 + 255) / 256, 256, 0, stream>>>(features, Xbf, NN * DF / 4);
    wt_pack<<<FTOT, 256, 0, stream>>>(W0, Wt);
    wct_pack<<<NC, 256, 0, stream>>>(Wc, Wct);

    gemm_h<<<dim3(NPAD / 128, FTOT / 128), 256, 0, stream>>>(Xbf, Wt, Ht);
    f12_kern<<<dim3((NPAD + 255) / 256, NH), 256, 0, stream>>>(Ht, a10, a20, f1, f2, HID);
    rarb_kern<<<NH, 256, 0, stream>>>(f1, f2, RA, RB);

    attn_main<<<dim3(63, NH), 192, 0, stream>>>(Ht, mask, RA, RB, f2, x2);

    gemm_hc<<<dim3(NPAD / 128, 8), 256, 0, stream>>>(Wct, x2, pkhc);
    merge_hc<<<dim3((NPAD + 255) / 256, NC), 256, 0, stream>>>(pkhc, hct);
    f12_kern<<<dim3((NPAD + 255) / 256, 1), 256, 0, stream>>>(hct, a1c, a2c, f1c, f2c, NC);
    rarb_kern<<<1, 256, 0, stream>>>(f1c, f2c, RAc, RBc);

    cls_part<<<dim3(47, 4), 256, 0, stream>>>(hct, mask, RAc, RBc, f2c, pacc, pdsum);
    cls_merge<<<750, 256, 0, stream>>>(pacc, pdsum, out);
}

// Round 6
// 677.438 us; speedup vs baseline: 1.6682x; 1.0012x over previous
//
#include <hip/hip_runtime.h>
#include <hip/hip_bf16.h>

#define NN 6000
#define NPAD 6016      // 94*64
#define DF 512
#define HID 256
#define NH 8
#define NC 32
#define FTOT 2048
#define MSTR 96        // u64 words per mask row
#define NJB (NPAD / 64)
#define L2E 1.4426950408889634f

using short8 = __attribute__((ext_vector_type(8))) short;
using f32x16 = __attribute__((ext_vector_type(16))) float;
using f32x4  = __attribute__((ext_vector_type(4))) float;

__device__ __forceinline__ unsigned short f2bf(float f) {
    unsigned int u = __float_as_uint(f);
    return (unsigned short)((u + 0x7fffu + ((u >> 16) & 1u)) >> 16);
}
__device__ __forceinline__ float bf2f(unsigned short s) {
    return __uint_as_float(((unsigned int)s) << 16);
}
// async global->LDS, 16B per lane; LDS dest = wave-uniform base + lane*16
__device__ __forceinline__ void gl16(const void* g, void* l) {
    __builtin_amdgcn_global_load_lds(
        (const __attribute__((address_space(1))) unsigned int*)g,
        (__attribute__((address_space(3))) unsigned int*)l, 16, 0, 0);
}

// ---------------- prep kernels (verified r3/r4) ----------------

__global__ void pack_bits(const int* __restrict__ adj, unsigned char* __restrict__ maskb) {
    int row = blockIdx.y;
    int b = blockIdx.x * 256 + threadIdx.x;     // byte index 0..767
    if (b >= 768) return;
    int j0 = b * 8;
    unsigned int v = 0;
    if (j0 + 7 < NN) {
        const int4* p = (const int4*)(adj + (size_t)row * NN + j0);
        int4 a = p[0], c = p[1];
        v = (unsigned)((a.x>0) | ((a.y>0)<<1) | ((a.z>0)<<2) | ((a.w>0)<<3)
          | ((c.x>0)<<4) | ((c.y>0)<<5) | ((c.z>0)<<6) | ((c.w>0)<<7));
    }
    maskb[(size_t)row * 768 + b] = (unsigned char)v;
}

__global__ void cast_x4(const float* __restrict__ x, unsigned short* __restrict__ xb, int n4) {
    int i = blockIdx.x * 256 + threadIdx.x;
    if (i >= n4) return;
    float4 v = ((const float4*)x)[i];
    unsigned long long pk = (unsigned long long)f2bf(v.x)
        | ((unsigned long long)f2bf(v.y) << 16)
        | ((unsigned long long)f2bf(v.z) << 32)
        | ((unsigned long long)f2bf(v.w) << 48);
    ((unsigned long long*)xb)[i] = pk;
}

__global__ void wt_pack(const float* __restrict__ W0, unsigned short* __restrict__ Wt) {
    int fp = blockIdx.x;                 // h*256+f
    int h = fp >> 8, f = fp & 255;
    for (int k = threadIdx.x; k < DF; k += 256)
        Wt[(size_t)fp * DF + k] = f2bf(W0[(((size_t)h * DF + k) << 8) | f]);
}

__global__ void wct_pack(const float* __restrict__ Wc, unsigned short* __restrict__ Wct) {
    int c = blockIdx.x;
    for (int k = threadIdx.x; k < FTOT; k += 256)
        Wct[(size_t)c * FTOT + k] = f2bf(Wc[(size_t)k * NC + c]);
}

// ---------------- GEMM1 (verified r3): Ht[f][i] = sum_k X[i][k] W[k][f] ----------------
__global__ __launch_bounds__(256, 2) void gemm_h(const unsigned short* __restrict__ A,
                                                 const unsigned short* __restrict__ B,
                                                 unsigned short* __restrict__ Ht) {
    __shared__ __align__(16) unsigned short As[128 * 64];
    __shared__ __align__(16) unsigned short Bs[128 * 64];
    const int w = threadIdx.x >> 6, l = threadIdx.x & 63;
    const int lrow = l & 31, kh = l >> 5;
    const int wm = w >> 1, wn = w & 1;
    const int mbase = blockIdx.x * 128, nbase = blockIdx.y * 128;
    const int srcc = (l & 7) ^ (l >> 3);
    f32x16 acc[2][2];
#pragma unroll
    for (int i = 0; i < 2; ++i)
#pragma unroll
        for (int j = 0; j < 2; ++j) acc[i][j] = (f32x16)0.0f;

#pragma unroll 1
    for (int kb = 0; kb < DF / 64; ++kb) {
        __syncthreads();
#pragma unroll
        for (int q = 0; q < 4; ++q) {
            int c = q * 4 + w;
            int r = c * 8 + (l >> 3);
            int arow = mbase + r; if (arow > NN - 1) arow = NN - 1;
            gl16(A + (size_t)arow * DF + kb * 64 + srcc * 8, (char*)As + c * 1024);
            gl16(B + (size_t)(nbase + r) * DF + kb * 64 + srcc * 8, (char*)Bs + c * 1024);
        }
        __syncthreads();
#pragma unroll
        for (int kk = 0; kk < 4; ++kk) {
            short8 av[2], bv[2];
#pragma unroll
            for (int mt = 0; mt < 2; ++mt) {
                int r = wm * 64 + mt * 32 + lrow;
                av[mt] = *(const short8*)((const char*)As + r * 128 + ((((kk << 1) | kh) ^ (r & 7)) << 4));
            }
#pragma unroll
            for (int ft = 0; ft < 2; ++ft) {
                int r = wn * 64 + ft * 32 + lrow;
                bv[ft] = *(const short8*)((const char*)Bs + r * 128 + ((((kk << 1) | kh) ^ (r & 7)) << 4));
            }
#pragma unroll
            for (int mt = 0; mt < 2; ++mt)
#pragma unroll
                for (int ft = 0; ft < 2; ++ft)
                    acc[mt][ft] = __builtin_amdgcn_mfma_f32_32x32x16_bf16(av[mt], bv[ft], acc[mt][ft], 0, 0, 0);
        }
    }
#pragma unroll
    for (int mt = 0; mt < 2; ++mt)
#pragma unroll
        for (int ft = 0; ft < 2; ++ft) {
            size_t n = nbase + wn * 64 + ft * 32 + lrow;
#pragma unroll
            for (int g = 0; g < 4; ++g) {
                int m0 = mbase + wm * 64 + mt * 32 + (g << 3) + (kh << 2);
                unsigned long long pk =
                    (unsigned long long)f2bf(acc[mt][ft][g * 4 + 0]) |
                    ((unsigned long long)f2bf(acc[mt][ft][g * 4 + 1]) << 16) |
                    ((unsigned long long)f2bf(acc[mt][ft][g * 4 + 2]) << 32) |
                    ((unsigned long long)f2bf(acc[mt][ft][g * 4 + 3]) << 48);
                *(unsigned long long*)(Ht + n * NPAD + m0) = pk;
            }
        }
}

// ---------------- f1/f2, pre-scaled by log2e (exp2 path downstream) ----------------
__global__ void f12_kern(const unsigned short* __restrict__ Ht, const float* __restrict__ a1,
                         const float* __restrict__ a2, float* __restrict__ f1, float* __restrict__ f2,
                         int fdim) {
    int h = blockIdx.y;
    int i = blockIdx.x * 256 + threadIdx.x;
    if (i >= NPAD) return;
    float s1 = 0.f, s2 = 0.f;
    const unsigned short* base = Ht + (size_t)h * fdim * NPAD + i;
    for (int f = 0; f < fdim; ++f) {
        float v = bf2f(base[(size_t)f * NPAD]);
        s1 = fmaf(v, a1[h * fdim + f], s1);
        s2 = fmaf(v, a2[h * fdim + f], s2);
    }
    f1[(size_t)h * NPAD + i] = s1 * L2E;
    f2[(size_t)h * NPAD + i] = s2 * L2E;
}

// per-head global max -> RA/RB (verified r5; inputs already log2e-scaled)
__global__ void rarb_kern(const float* __restrict__ f1all, const float* __restrict__ f2all,
                          float* __restrict__ RA, float* __restrict__ RB) {
    int h = blockIdx.x;
    __shared__ float red[8];
    const float* f2h = f2all + (size_t)h * NPAD;
    float m = -3.0e38f;
    for (int i = threadIdx.x; i < NN; i += 256) m = fmaxf(m, f2h[i]);
    for (int off = 32; off; off >>= 1) m = fmaxf(m, __shfl_xor(m, off));
    if ((threadIdx.x & 63) == 0) red[threadIdx.x >> 6] = m;
    __syncthreads();
    if (threadIdx.x == 0)
        red[4] = fmaxf(fmaxf(red[0], red[1]), fmaxf(red[2], red[3]));
    __syncthreads();
    float Mh = red[4];
    for (int i = threadIdx.x; i < NPAD; i += 256) {
        float F1 = (i < NN) ? f1all[(size_t)h * NPAD + i] : 0.f;
        float t2 = F1 + Mh;
        float Mi = fmaxf(t2, 0.2f * t2);
        RA[(size_t)h * NPAD + i] = F1 - Mi;
        RB[(size_t)h * NPAD + i] = 0.2f * F1 - Mi;
    }
}

// ---------------- main attention v3: f-split halves, 32KB LDS, head->XCD pinning ----------------
// grid 1008 (1-D): h = bid&7 (== XCD via round-robin), fh = (bid>>3)&1, bx = bid>>4.
__global__ __launch_bounds__(192) void attn_main(
    const unsigned short* __restrict__ Ht,
    const unsigned long long* __restrict__ mask,
    const float* __restrict__ RA, const float* __restrict__ RB,
    const float* __restrict__ F2,
    unsigned short* __restrict__ x2)
{
    __shared__ __align__(16) unsigned short htile[2 * 128 * 64];   // 32 KB dbuf, swizzled [128][64]
    const int bid = blockIdx.x;
    const int h = bid & 7;
    const int fh = (bid >> 3) & 1;
    const int bx = bid >> 4;
    const int w = threadIdx.x >> 6, l = threadIdx.x & 63;
    const int lrow = l & 31, kh = l >> 5;
    const int rowbase = bx * 96;
    const int myrow = rowbase + w * 32 + lrow;
    const bool act = myrow < NN;
    const unsigned short* Hh = Ht + ((size_t)h * HID + fh * 128) * NPAD;
    const float* F2h = F2 + (size_t)h * NPAD;
    const float ra = RA[(size_t)h * NPAD + myrow], rb = RB[(size_t)h * NPAD + myrow];
    const int srcc = (l & 7) ^ (l >> 3);
    float dsum = 0.f;
    f32x16 acc[4];
#pragma unroll
    for (int i = 0; i < 4; ++i) acc[i] = (f32x16)0.0f;

    auto STAGE = [&](int b, int jb) {
        for (int c = w; c < 16; c += 3) {
            int f = c * 8 + (l >> 3);
            gl16(Hh + (size_t)f * NPAD + jb * 64 + srcc * 8, (char*)htile + b * 16384 + c * 1024);
        }
    };
    STAGE(0, 0);
    __syncthreads();           // buf0 ready
    unsigned long long mw = act ? mask[(size_t)myrow * MSTR] : 0ull;
    int cur = 0;
#pragma unroll 1
    for (int jb = 0; jb < NJB; ++jb) {
        if (jb + 1 < NJB) STAGE(cur ^ 1, jb + 1);   // async prefetch next tile
        unsigned long long mw_n = (act && jb + 1 < NJB) ? mask[(size_t)myrow * MSTR + jb + 1] : 0ull;
        {
            const char* tb = (const char*)htile + cur * 16384;
#pragma unroll
            for (int kk = 0; kk < 4; ++kk) {
                unsigned int mbyte = (unsigned int)((mw >> (kk * 16 + kh * 8)) & 0xffull);
                int j0 = jb * 64 + kk * 16 + kh * 8;
                f32x4 fa0 = *(const f32x4*)(F2h + j0);
                f32x4 fa1 = *(const f32x4*)(F2h + j0 + 4);
                float p[8];
#pragma unroll
                for (int e = 0; e < 8; ++e) {
                    float fe = (e < 4) ? fa0[e & 3] : fa1[e & 3];
                    float pe = exp2f(fmaxf(ra + fe, rb + 0.2f * fe));
                    p[e] = (mbyte & (1u << e)) ? pe : 0.f;
                }
                // truncating bf16 pack; denominator over the SAME truncated values (r4-verified)
                union { unsigned int u[4]; short8 s8; } cv;
#pragma unroll
                for (int q = 0; q < 4; ++q) {
                    unsigned int up = __builtin_amdgcn_perm(__float_as_uint(p[2 * q + 1]),
                                                            __float_as_uint(p[2 * q]), 0x07060302u);
                    cv.u[q] = up;
                    dsum += __uint_as_float(up << 16);
                    dsum += __uint_as_float(up & 0xffff0000u);
                }
                __builtin_amdgcn_s_setprio(1);
#pragma unroll
                for (int ft = 0; ft < 4; ++ft) {
                    int fr = ft * 32 + lrow;
                    short8 bfrag = *(const short8*)(tb + fr * 128 + (((kk * 2 + kh) * 16) ^ ((fr & 7) << 4)));
                    acc[ft] = __builtin_amdgcn_mfma_f32_32x32x16_bf16(cv.s8, bfrag, acc[ft], 0, 0, 0);
                }
                __builtin_amdgcn_s_setprio(0);
            }
        }
        __syncthreads();       // next tile landed; all reads of cur done
        cur ^= 1;
        mw = mw_n;
    }

    dsum += __shfl_xor(dsum, 32);
    float dinv = (dsum > 0.f) ? (1.0f / dsum) : 0.f;
    float rcp16[16];
#pragma unroll
    for (int g = 0; g < 4; ++g)
#pragma unroll
        for (int rr = 0; rr < 4; ++rr)
            rcp16[g * 4 + rr] = __shfl(dinv, (g << 3) + (kh << 2) + rr);

#pragma unroll
    for (int ft = 0; ft < 4; ++ft)
#pragma unroll
        for (int g = 0; g < 4; ++g)
#pragma unroll
            for (int rr = 0; rr < 4; ++rr) {
                int grow = rowbase + w * 32 + (g << 3) + (kh << 2) + rr;
                if (grow < NN) {
                    float v = acc[ft][g * 4 + rr] * rcp16[g * 4 + rr];
                    v = (v > 0.f) ? v : (__expf(v) - 1.f);
                    x2[(size_t)grow * FTOT + h * HID + fh * 128 + ft * 32 + lrow] = f2bf(v);
                }
            }
}

// ---------------- GEMM2: split-K x8 -> f32 partials (verified r5) ----------------
__global__ __launch_bounds__(256, 2) void gemm_hc(const unsigned short* __restrict__ A,
                                                  const unsigned short* __restrict__ B,
                                                  float* __restrict__ pk) {
    int w = threadIdx.x >> 6, l = threadIdx.x & 63;
    int lrow = l & 31, kh = l >> 5;
    int q = blockIdx.y;
    int nbase = blockIdx.x * 128 + w * 32;
    int brow = nbase + lrow; if (brow > NN - 1) brow = NN - 1;
    f32x16 acc = (f32x16)0.0f;
    const short8* ap = (const short8*)(A + (size_t)lrow * FTOT + q * 256 + kh * 8);
    const short8* bp = (const short8*)(B + (size_t)brow * FTOT + q * 256 + kh * 8);
#pragma unroll
    for (int kk = 0; kk < 16; ++kk) {
        short8 af = ap[kk * 2];
        short8 bf = bp[kk * 2];
        acc = __builtin_amdgcn_mfma_f32_32x32x16_bf16(af, bf, acc, 0, 0, 0);
    }
    int i = nbase + lrow;
#pragma unroll
    for (int g = 0; g < 4; ++g) {
        int c0 = (g << 3) + (kh << 2);
#pragma unroll
        for (int r = 0; r < 4; ++r)
            pk[((size_t)q * NC + c0 + r) * NPAD + i] = acc[g * 4 + r];
    }
}

__global__ void merge_hc(const float* __restrict__ pk, unsigned short* __restrict__ hct) {
    int i = blockIdx.x * 256 + threadIdx.x;
    int c = blockIdx.y;
    if (i >= NPAD) return;
    float s = 0.f;
#pragma unroll
    for (int q = 0; q < 8; ++q) s += pk[((size_t)q * NC + c) * NPAD + i];
    hct[(size_t)c * NPAD + i] = f2bf(s);
}

// ---------------- classifier attention: j-split 8 ways ----------------
__global__ __launch_bounds__(256, 2) void cls_part(
    const unsigned short* __restrict__ hctb,
    const unsigned long long* __restrict__ mask,
    const float* __restrict__ RAc, const float* __restrict__ RBc,
    const float* __restrict__ F2c,
    float* __restrict__ pacc, float* __restrict__ pdsum)
{
    __shared__ __align__(16) unsigned short ctile[2 * NC * 64];   // 8 KB dbuf
    const int w = threadIdx.x >> 6, l = threadIdx.x & 63;
    const int lrow = l & 31, kh = l >> 5;
    const int q = blockIdx.y;
    const int rowbase = blockIdx.x * 128;
    const int myrow = rowbase + w * 32 + lrow;
    const bool act = myrow < NN;
    float ra = RAc[myrow], rb = RBc[myrow];
    const int srcc = (l & 7) ^ (l >> 3);
    const int JB0 = q * 12, JB1 = (JB0 + 12 < NJB) ? JB0 + 12 : NJB;
    float dsum = 0.f;
    f32x16 acc = (f32x16)0.0f;

    auto STAGE = [&](int b, int jb) {
        int f = w * 8 + (l >> 3);
        gl16(hctb + (size_t)f * NPAD + jb * 64 + srcc * 8, (char*)ctile + b * 4096 + w * 1024);
    };
    STAGE(0, JB0);
    __syncthreads();
    int cur = 0;
#pragma unroll 1
    for (int jb = JB0; jb < JB1; ++jb) {
        if (jb + 1 < JB1) STAGE(cur ^ 1, jb + 1);
        {
            unsigned long long mword = act ? mask[(size_t)myrow * MSTR + jb] : 0ull;
            const char* tb = (const char*)ctile + cur * 4096;
#pragma unroll
            for (int kk = 0; kk < 4; ++kk) {
                unsigned int mbyte = (unsigned int)((mword >> (kk * 16 + kh * 8)) & 0xffull);
                int j0 = jb * 64 + kk * 16 + kh * 8;
                f32x4 fa0 = *(const f32x4*)(F2c + j0);
                f32x4 fa1 = *(const f32x4*)(F2c + j0 + 4);
                float p[8];
#pragma unroll
                for (int e = 0; e < 8; ++e) {
                    float fe = (e < 4) ? fa0[e & 3] : fa1[e & 3];
                    float pe = exp2f(fmaxf(ra + fe, rb + 0.2f * fe));
                    p[e] = (mbyte & (1u << e)) ? pe : 0.f;
                }
                union { unsigned int u[4]; short8 s8; } cv;
#pragma unroll
                for (int t = 0; t < 4; ++t) {
                    unsigned int up = __builtin_amdgcn_perm(__float_as_uint(p[2 * t + 1]),
                                                            __float_as_uint(p[2 * t]), 0x07060302u);
                    cv.u[t] = up;
                    dsum += __uint_as_float(up << 16);
                    dsum += __uint_as_float(up & 0xffff0000u);
                }
                short8 bfrag = *(const short8*)(tb + lrow * 128 + (((kk * 2 + kh) * 16) ^ ((lrow & 7) << 4)));
                acc = __builtin_amdgcn_mfma_f32_32x32x16_bf16(cv.s8, bfrag, acc, 0, 0, 0);
            }
        }
        __syncthreads();
        cur ^= 1;
    }
    dsum += __shfl_xor(dsum, 32);
    if (kh == 0) pdsum[(size_t)q * NPAD + myrow] = dsum;
#pragma unroll
    for (int g = 0; g < 4; ++g)
#pragma unroll
        for (int rr = 0; rr < 4; ++rr) {
            int i = rowbase + w * 32 + (g << 3) + (kh << 2) + rr;
            pacc[((size_t)q * NPAD + i) * NC + lrow] = acc[g * 4 + rr];
        }
}

__global__ void cls_merge(const float* __restrict__ pacc, const float* __restrict__ pdsum,
                          float* __restrict__ outp) {
    int i = blockIdx.x * 8 + (threadIdx.x >> 5);
    int c = threadIdx.x & 31;
    if (i >= NN) return;
    float num = 0.f, den = 0.f;
#pragma unroll
    for (int q = 0; q < 8; ++q) {
        num += pacc[((size_t)q * NPAD + i) * NC + c];
        den += pdsum[(size_t)q * NPAD + i];
    }
    outp[(size_t)i * NC + c] = (den > 0.f) ? num / den : 0.f;
}

// ---------------- launcher ----------------
extern "C" void kernel_launch(void* const* d_in, const int* in_sizes, int n_in,
                              void* d_out, int out_size, void* d_ws, size_t ws_size,
                              hipStream_t stream) {
    const float* features = (const float*)d_in[0];
    const int*   adj      = (const int*)d_in[1];
    const float* W0       = (const float*)d_in[2];
    const float* a10      = (const float*)d_in[3];
    const float* a20      = (const float*)d_in[4];
    const float* Wc       = (const float*)d_in[5];
    const float* a1c      = (const float*)d_in[6];
    const float* a2c      = (const float*)d_in[7];
    float* out = (float*)d_out;

    char* p = (char*)d_ws;
    auto alloc = [&](size_t bytes) { char* r = p; p += (bytes + 255) & ~(size_t)255; return r; };
    unsigned long long* mask = (unsigned long long*)alloc((size_t)NN * MSTR * 8);
    unsigned short* Xbf = (unsigned short*)alloc((size_t)NN * DF * 2);
    unsigned short* Wt  = (unsigned short*)alloc((size_t)FTOT * DF * 2);
    unsigned short* Ht  = (unsigned short*)alloc((size_t)FTOT * NPAD * 2);
    unsigned short* x2  = (unsigned short*)alloc((size_t)NN * FTOT * 2);
    unsigned short* Wct = (unsigned short*)alloc((size_t)NC * FTOT * 2);
    unsigned short* hct = (unsigned short*)alloc((size_t)NC * NPAD * 2);
    float* f1  = (float*)alloc((size_t)NH * NPAD * 4);
    float* f2  = (float*)alloc((size_t)NH * NPAD * 4);
    float* RA  = (float*)alloc((size_t)NH * NPAD * 4);
    float* RB  = (float*)alloc((size_t)NH * NPAD * 4);
    float* f1c  = (float*)alloc((size_t)NPAD * 4);
    float* f2c  = (float*)alloc((size_t)NPAD * 4);
    float* RAc  = (float*)alloc((size_t)NPAD * 4);
    float* RBc  = (float*)alloc((size_t)NPAD * 4);
    // overlays on dead Xbf+Wt (8.25 MB): pkhc 6.16 MB, then pacc 6.16 MB + pdsum 0.19 MB
    float* pkhc  = (float*)Xbf;
    float* pacc  = (float*)Xbf;
    float* pdsum = pacc + (size_t)8 * NPAD * NC;

    pack_bits<<<dim3(3, NN), 256, 0, stream>>>(adj, (unsigned char*)mask);
    cast_x4<<<(NN * DF / 4 + 255) / 256, 256, 0, stream>>>(features, Xbf, NN * DF / 4);
    wt_pack<<<FTOT, 256, 0, stream>>>(W0, Wt);
    wct_pack<<<NC, 256, 0, stream>>>(Wc, Wct);

    gemm_h<<<dim3(NPAD / 128, FTOT / 128), 256, 0, stream>>>(Xbf, Wt, Ht);
    f12_kern<<<dim3((NPAD + 255) / 256, NH), 256, 0, stream>>>(Ht, a10, a20, f1, f2, HID);
    rarb_kern<<<NH, 256, 0, stream>>>(f1, f2, RA, RB);

    attn_main<<<dim3(63 * 2 * NH), 192, 0, stream>>>(Ht, mask, RA, RB, f2, x2);

    gemm_hc<<<dim3(NPAD / 128, 8), 256, 0, stream>>>(Wct, x2, pkhc);
    merge_hc<<<dim3((NPAD + 255) / 256, NC), 256, 0, stream>>>(pkhc, hct);
    f12_kern<<<dim3((NPAD + 255) / 256, 1), 256, 0, stream>>>(hct, a1c, a2c, f1c, f2c, NC);
    rarb_kern<<<1, 256, 0, stream>>>(f1c, f2c, RAc, RBc);

    cls_part<<<dim3(47, 8), 256, 0, stream>>>(hct, mask, RAc, RBc, f2c, pacc, pdsum);
    cls_merge<<<750, 256, 0, stream>>>(pacc, pdsum, out);
}